// Round 4
// baseline (150.455 us; speedup 1.0000x reference)
//
#include <hip/hip_runtime.h>
#include <math.h>

#define N_NODES 1024
#define DIM     256

typedef float f32x2 __attribute__((ext_vector_type(2)));
typedef float f32x4 __attribute__((ext_vector_type(4)));

// ---------------------------------------------------------------------------
// Packed-f32 helpers (VOP3P). op_sel[i] picks the source half feeding the LOW
// result; op_sel_hi[i] the half feeding the HIGH result.
//   pk_add_blo: d.lo = a.lo + b.lo ; d.hi = a.lo + b.hi   (broadcast a.lo)
//   pk_add_bhi: d.lo = a.hi + b.lo ; d.hi = a.hi + b.hi   (broadcast a.hi)
//   pk_fma_wlo: acc  += h * {w.lo, w.lo}
//   pk_fma_whi: acc  += h * {w.hi, w.hi}
// ---------------------------------------------------------------------------
__device__ __forceinline__ f32x2 pk_add_blo(f32x2 a, f32x2 b) {
    f32x2 d;
    asm("v_pk_add_f32 %0, %1, %2 op_sel:[0,0] op_sel_hi:[0,1]"
        : "=v"(d) : "v"(a), "v"(b));
    return d;
}
__device__ __forceinline__ f32x2 pk_add_bhi(f32x2 a, f32x2 b) {
    f32x2 d;
    asm("v_pk_add_f32 %0, %1, %2 op_sel:[1,0] op_sel_hi:[1,1]"
        : "=v"(d) : "v"(a), "v"(b));
    return d;
}
__device__ __forceinline__ void pk_fma_wlo(f32x2& acc, f32x2 h, f32x2 w) {
    asm("v_pk_fma_f32 %0, %1, %2, %0 op_sel:[0,0,0] op_sel_hi:[1,0,1]"
        : "+v"(acc) : "v"(h), "v"(w));
}
__device__ __forceinline__ void pk_fma_whi(f32x2& acc, f32x2 h, f32x2 w) {
    asm("v_pk_fma_f32 %0, %1, %2, %0 op_sel:[0,1,0] op_sel_hi:[1,1,1]"
        : "+v"(acc) : "v"(h), "v"(w));
}
__device__ __forceinline__ f32x2 relu2(f32x2 x) {
    return __builtin_elementwise_max(x, (f32x2)0.0f);
}

// ---------------------------------------------------------------------------
// Kernel 1 (unchanged, verified): At[d][i] = nodes@Wa.T + b1, Bt[d][i] = nodes@Wb.T
// stored transposed [d][node].
// ---------------------------------------------------------------------------
__global__ __launch_bounds__(256) void k1_gemm(
    const float* __restrict__ nodes, const float* __restrict__ W1,
    const float* __restrict__ b1, float* __restrict__ At, float* __restrict__ Bt)
{
    __shared__ float nt[64][34];
    __shared__ float wa[64][34];
    __shared__ float wb[64][34];

    const int i0 = (blockIdx.x & 31) * 32;
    const int d0 = (blockIdx.x >> 5) * 32;
    const int t  = threadIdx.x;
    const int tx = t & 15;
    const int ty = t >> 4;

    float aA00=0.f,aA01=0.f,aA10=0.f,aA11=0.f;
    float aB00=0.f,aB01=0.f,aB10=0.f,aB11=0.f;

    const int r = t >> 3;
    const int c = (t & 7) * 8;

    for (int k0 = 0; k0 < DIM; k0 += 64) {
        const float* sn = nodes + (i0 + r) * DIM + k0 + c;
        float4 n0 = *(const float4*)(sn);
        float4 n1 = *(const float4*)(sn + 4);
        const float* sa = W1 + (d0 + r) * (2 * DIM) + k0 + c;
        float4 a0 = *(const float4*)(sa);
        float4 a1 = *(const float4*)(sa + 4);
        const float* sb = sa + DIM;
        float4 q0 = *(const float4*)(sb);
        float4 q1 = *(const float4*)(sb + 4);

        __syncthreads();

        nt[c+0][r]=n0.x; nt[c+1][r]=n0.y; nt[c+2][r]=n0.z; nt[c+3][r]=n0.w;
        nt[c+4][r]=n1.x; nt[c+5][r]=n1.y; nt[c+6][r]=n1.z; nt[c+7][r]=n1.w;
        wa[c+0][r]=a0.x; wa[c+1][r]=a0.y; wa[c+2][r]=a0.z; wa[c+3][r]=a0.w;
        wa[c+4][r]=a1.x; wa[c+5][r]=a1.y; wa[c+6][r]=a1.z; wa[c+7][r]=a1.w;
        wb[c+0][r]=q0.x; wb[c+1][r]=q0.y; wb[c+2][r]=q0.z; wb[c+3][r]=q0.w;
        wb[c+4][r]=q1.x; wb[c+5][r]=q1.y; wb[c+6][r]=q1.z; wb[c+7][r]=q1.w;

        __syncthreads();

        #pragma unroll 16
        for (int k = 0; k < 64; ++k) {
            float2 av = *(const float2*)&nt[k][tx*2];
            float2 pv = *(const float2*)&wa[k][ty*2];
            float2 qv = *(const float2*)&wb[k][ty*2];
            aA00 += av.x*pv.x; aA01 += av.x*pv.y;
            aA10 += av.y*pv.x; aA11 += av.y*pv.y;
            aB00 += av.x*qv.x; aB01 += av.x*qv.y;
            aB10 += av.y*qv.x; aB11 += av.y*qv.y;
        }
    }

    const int i = i0 + tx*2;
    const int d = d0 + ty*2;
    const float bb0 = b1[d], bb1 = b1[d+1];
    At[(d  )*N_NODES + i  ] = aA00 + bb0;
    At[(d+1)*N_NODES + i  ] = aA01 + bb1;
    At[(d  )*N_NODES + i+1] = aA10 + bb0;
    At[(d+1)*N_NODES + i+1] = aA11 + bb1;
    Bt[(d  )*N_NODES + i  ] = aB00;
    Bt[(d+1)*N_NODES + i  ] = aB01;
    Bt[(d  )*N_NODES + i+1] = aB10;
    Bt[(d+1)*N_NODES + i+1] = aB11;
}

// ---------------------------------------------------------------------------
// Kernel 2 v2: out[i,j] = sigmoid( sum_d relu(At[d][i]+Bt[d][j]) * w2[d] + b2 )
// No LDS, no barriers. At/Bt (2 MB) are L2-resident; per-wave reads are
// broadcast (a: 4 distinct float2) + coalesced (b: 16 contiguous float4).
// Grid: 512 blocks (32 i-tiles x 16 j-tiles) = 2 blocks/CU = 2 waves/SIMD.
// Tile 32(i) x 64(j); 256 threads, micro 2x4; packed-f32 core: 2 VALU
// instrs per output element (pk_add + 2x v_max + pk_fma per 2 elements).
// ---------------------------------------------------------------------------
__global__ __launch_bounds__(256, 2) void k2_pair(
    const float* __restrict__ At, const float* __restrict__ Bt,
    const float* __restrict__ W2, const float* __restrict__ b2,
    float* __restrict__ out)
{
    const int i0 = (blockIdx.x & 31) * 32;   // 32 i-tiles
    const int j0 = (blockIdx.x >> 5) * 64;   // 16 j-tiles
    const int t  = threadIdx.x;
    const int tx = t & 15;                   // j-group: 4 consecutive cols
    const int ty = t >> 4;                   // i-group: 2 consecutive rows

    const float* __restrict__ Ar = At + i0 + ty*2;   // lane-const offset
    const float* __restrict__ Br = Bt + j0 + tx*4;

    f32x2 acc00 = {0.f,0.f}, acc01 = {0.f,0.f};   // row i,   cols (0,1) (2,3)
    f32x2 acc10 = {0.f,0.f}, acc11 = {0.f,0.f};   // row i+1

    #pragma unroll 4
    for (int d = 0; d < DIM; d += 2) {
        f32x2 wp = *(const f32x2*)(W2 + d);       // uniform -> scalar load

        // --- d (uses w.lo) ---
        {
            f32x2 a2 = *(const f32x2*)(Ar + d*N_NODES);
            f32x4 b4 = *(const f32x4*)(Br + d*N_NODES);
            f32x2 b01 = __builtin_shufflevector(b4, b4, 0, 1);
            f32x2 b23 = __builtin_shufflevector(b4, b4, 2, 3);
            f32x2 h;
            h = relu2(pk_add_blo(a2, b01)); pk_fma_wlo(acc00, h, wp);
            h = relu2(pk_add_blo(a2, b23)); pk_fma_wlo(acc01, h, wp);
            h = relu2(pk_add_bhi(a2, b01)); pk_fma_wlo(acc10, h, wp);
            h = relu2(pk_add_bhi(a2, b23)); pk_fma_wlo(acc11, h, wp);
        }
        // --- d+1 (uses w.hi) ---
        {
            f32x2 a2 = *(const f32x2*)(Ar + (d+1)*N_NODES);
            f32x4 b4 = *(const f32x4*)(Br + (d+1)*N_NODES);
            f32x2 b01 = __builtin_shufflevector(b4, b4, 0, 1);
            f32x2 b23 = __builtin_shufflevector(b4, b4, 2, 3);
            f32x2 h;
            h = relu2(pk_add_blo(a2, b01)); pk_fma_whi(acc00, h, wp);
            h = relu2(pk_add_blo(a2, b23)); pk_fma_whi(acc01, h, wp);
            h = relu2(pk_add_bhi(a2, b01)); pk_fma_whi(acc10, h, wp);
            h = relu2(pk_add_bhi(a2, b23)); pk_fma_whi(acc11, h, wp);
        }
    }

    const float bb = b2[0];
    const int r0 = i0 + ty*2;
    const int c0 = j0 + tx*4;

    f32x4 o0 = { acc00.x + bb, acc00.y + bb, acc01.x + bb, acc01.y + bb };
    f32x4 o1 = { acc10.x + bb, acc10.y + bb, acc11.x + bb, acc11.y + bb };
    #pragma unroll
    for (int e = 0; e < 4; ++e) {
        o0[e] = 1.0f / (1.0f + __expf(-o0[e]));
        o1[e] = 1.0f / (1.0f + __expf(-o1[e]));
    }
    *(f32x4*)&out[(r0    ) * N_NODES + c0] = o0;
    *(f32x4*)&out[(r0 + 1) * N_NODES + c0] = o1;
}

extern "C" void kernel_launch(void* const* d_in, const int* in_sizes, int n_in,
                              void* d_out, int out_size, void* d_ws, size_t ws_size,
                              hipStream_t stream) {
    const float* nodes = (const float*)d_in[0];   // (1024, 256)
    const float* W1    = (const float*)d_in[1];   // (256, 512)
    const float* b1    = (const float*)d_in[2];   // (256,)
    const float* W2    = (const float*)d_in[3];   // (1, 256)
    const float* b2    = (const float*)d_in[4];   // (1,)
    float* out = (float*)d_out;                   // (1024, 1024)

    float* At = (float*)d_ws;                     // [256][1024] = 1 MB
    float* Bt = At + DIM * N_NODES;               // [256][1024] = 1 MB

    k1_gemm<<<256, 256, 0, stream>>>(nodes, W1, b1, At, Bt);
    k2_pair<<<512, 256, 0, stream>>>(At, Bt, W2, b2, out);
}

// Round 5
// 99.531 us; speedup vs baseline: 1.5116x; 1.5116x over previous
//
#include <hip/hip_runtime.h>
#include <math.h>

#define N_NODES 1024
#define DIM     256

// ---------------------------------------------------------------------------
// k1 v2: At[d][i] = sum_k nodes[i,k]*W1[d,k] + b1[d];  Bt[d][i] = ... W1[d,256+k]
// Outputs transposed [d][node] for k2's staging.
// Stage-once design: 32(i) x 16(d) tile, grid 32*16=512 blocks = 2/CU,
// ONE barrier, then pure LDS+VALU. LDS 67 KB/block -> 2 blocks/CU fits 160 KB.
//  - nodes tile staged transposed nt[k][i]  (pad 33, staggered k -> <=2-way)
//  - W panels staged transposed wa/wb[k][d] (pad 17, <=2-way)
// ---------------------------------------------------------------------------
__global__ __launch_bounds__(256, 2) void k1_gemm(
    const float* __restrict__ nodes, const float* __restrict__ W1,
    const float* __restrict__ b1, float* __restrict__ At, float* __restrict__ Bt)
{
    __shared__ float nt[DIM][33];   // nt[k][i_local], i_local < 32
    __shared__ float wa[DIM][17];   // wa[k][d_local], d_local < 16
    __shared__ float wb[DIM][17];

    const int t  = threadIdx.x;
    const int i0 = (blockIdx.x & 31) * 32;   // 32 i-tiles
    const int d0 = (blockIdx.x >> 5) * 16;   // 16 d-tiles

    // ---- stage nodes tile (transposed). thread: row s=t>>3 (i), k=rep*32+m*4.
    {
        const int m = t & 7;
        const int s = t >> 3;                // 0..31
        const float* src = nodes + (i0 + s) * DIM;
        #pragma unroll
        for (int rep = 0; rep < 8; ++rep) {
            const int k = rep * 32 + m * 4;
            float4 v = *(const float4*)(src + k);
            nt[k+0][s] = v.x; nt[k+1][s] = v.y;
            nt[k+2][s] = v.z; nt[k+3][s] = v.w;
        }
    }
    // ---- stage W panels (transposed). thread: row s=t>>4 (d), k=rep*64+m*4.
    {
        const int m = t & 15;
        const int s = t >> 4;                // 0..15
        const float* srcA = W1 + (d0 + s) * (2 * DIM);
        const float* srcB = srcA + DIM;
        #pragma unroll
        for (int rep = 0; rep < 4; ++rep) {
            const int k = rep * 64 + m * 4;
            float4 va = *(const float4*)(srcA + k);
            float4 vb = *(const float4*)(srcB + k);
            wa[k+0][s] = va.x; wa[k+1][s] = va.y;
            wa[k+2][s] = va.z; wa[k+3][s] = va.w;
            wb[k+0][s] = vb.x; wb[k+1][s] = vb.y;
            wb[k+2][s] = vb.z; wb[k+3][s] = vb.w;
        }
    }
    __syncthreads();

    const int tx = t & 15;   // i pair: i = i0 + tx*2
    const int ty = t >> 4;   // d:      d = d0 + ty
    float aA0 = 0.f, aA1 = 0.f, aB0 = 0.f, aB1 = 0.f;

    #pragma unroll 8
    for (int k = 0; k < DIM; ++k) {
        float2 av = *(const float2*)&nt[k][tx * 2];   // conflict-free (16 addrs, x4 bcast)
        float  wk = wa[k][ty];                        // 4 addrs, x16 broadcast
        float  vk = wb[k][ty];
        aA0 += av.x * wk;  aA1 += av.y * wk;
        aB0 += av.x * vk;  aB1 += av.y * vk;
    }

    const int d = d0 + ty;
    const int i = i0 + tx * 2;
    const float bb = b1[d];
    float2 oa; oa.x = aA0 + bb; oa.y = aA1 + bb;
    float2 ob; ob.x = aB0;      ob.y = aB1;
    *(float2*)&At[d * N_NODES + i] = oa;
    *(float2*)&Bt[d * N_NODES + i] = ob;
}

// ---------------------------------------------------------------------------
// k2 v3: out[i,j] = sigmoid( sum_d relu(At[d][i]+Bt[d][j]) * w2[d] + b2 )
// Stage-once: 32x32 output tile, grid 32*32=1024 blocks = 2/CU (2 waves/SIMD
// for latency hiding). Full 256-d A/B slabs in LDS (32KB+32KB, linear layout,
// coalesced float4 staging, conflict-free reads: per-d all lanes share d so
// row stride 32 is harmless; a-read broadcast x16, b-read spans banks).
// ONE barrier total; inner loop = 2x ds_read_b64 + 12 VALU per d (3 ops/elem,
// the VALU floor for this op). W2 read uniformly -> scalar loads.
// ---------------------------------------------------------------------------
__global__ __launch_bounds__(256, 2) void k2_pair(
    const float* __restrict__ At, const float* __restrict__ Bt,
    const float* __restrict__ W2, const float* __restrict__ b2,
    float* __restrict__ out)
{
    __shared__ float As[DIM][32];   // As[d][i_local]
    __shared__ float Bs[DIM][32];   // Bs[d][j_local]

    const int t  = threadIdx.x;
    const int i0 = (blockIdx.x & 31) * 32;   // 32 i-tiles
    const int j0 = (blockIdx.x >> 5) * 32;   // 32 j-tiles

    // ---- stage both slabs, fully coalesced (8 rows x 128B per wave-rep)
    #pragma unroll
    for (int rep = 0; rep < 8; ++rep) {
        const int flat = rep * 256 + t;      // 0..2047
        const int row  = flat >> 3;          // d
        const int c4   = (flat & 7) * 4;     // col
        *(float4*)&As[row][c4] = *(const float4*)(At + row * N_NODES + i0 + c4);
        *(float4*)&Bs[row][c4] = *(const float4*)(Bt + row * N_NODES + j0 + c4);
    }
    __syncthreads();

    const int tx = t & 15;   // j pair: j = j0 + tx*2
    const int ty = t >> 4;   // i pair: i = i0 + ty*2
    float acc00 = 0.f, acc01 = 0.f, acc10 = 0.f, acc11 = 0.f;

    #pragma unroll 8
    for (int d = 0; d < DIM; ++d) {
        const float w = W2[d];                        // uniform -> s_load
        float2 a = *(const float2*)&As[d][ty * 2];    // 4 addrs, x16 broadcast
        float2 b = *(const float2*)&Bs[d][tx * 2];    // 16 addrs, x4 broadcast
        acc00 += fmaxf(a.x + b.x, 0.f) * w;
        acc01 += fmaxf(a.x + b.y, 0.f) * w;
        acc10 += fmaxf(a.y + b.x, 0.f) * w;
        acc11 += fmaxf(a.y + b.y, 0.f) * w;
    }

    const float bb = b2[0];
    float2 o0, o1;
    o0.x = 1.0f / (1.0f + __expf(-(acc00 + bb)));
    o0.y = 1.0f / (1.0f + __expf(-(acc01 + bb)));
    o1.x = 1.0f / (1.0f + __expf(-(acc10 + bb)));
    o1.y = 1.0f / (1.0f + __expf(-(acc11 + bb)));

    const int r = i0 + ty * 2;
    const int c = j0 + tx * 2;
    *(float2*)&out[(r    ) * N_NODES + c] = o0;
    *(float2*)&out[(r + 1) * N_NODES + c] = o1;
}

extern "C" void kernel_launch(void* const* d_in, const int* in_sizes, int n_in,
                              void* d_out, int out_size, void* d_ws, size_t ws_size,
                              hipStream_t stream) {
    const float* nodes = (const float*)d_in[0];   // (1024, 256)
    const float* W1    = (const float*)d_in[1];   // (256, 512)
    const float* b1    = (const float*)d_in[2];   // (256,)
    const float* W2    = (const float*)d_in[3];   // (1, 256)
    const float* b2    = (const float*)d_in[4];   // (1,)
    float* out = (float*)d_out;                   // (1024, 1024)

    float* At = (float*)d_ws;                     // [256][1024] = 1 MB
    float* Bt = At + DIM * N_NODES;               // [256][1024] = 1 MB

    k1_gemm<<<512,  256, 0, stream>>>(nodes, W1, b1, At, Bt);
    k2_pair<<<1024, 256, 0, stream>>>(At, Bt, W2, b2, out);
}

// Round 7
// 94.107 us; speedup vs baseline: 1.5988x; 1.0576x over previous
//
#include <hip/hip_runtime.h>
#include <math.h>

#define N_NODES 1024
#define DIM     256

typedef float f32x2 __attribute__((ext_vector_type(2)));

__device__ __forceinline__ f32x2 relu2(f32x2 x) {
    return __builtin_elementwise_max(x, (f32x2)0.0f);
}

// ---------------------------------------------------------------------------
// k1 v3: At[d][i] = sum_k nodes[i,k]*W1[d,k] + b1[d];  Bt[d][i] = sum_k nodes[i,k]*W1[d,256+k]
// Outputs transposed [d][node].
// Tile 32(i) x 16(d), grid 512 = 2 blocks/CU. LDS 52 KB:
//   wab[k][d] = {Wa[d][k], Wb[d][k]} pairs, full k (stride 17 f32x2 -> 4-way
//   write conflict only at stage time, conflict-free broadcast reads)
//   nt[k][i]  = nodes^T, k-chunked 128 (stride 34 floats: even -> aligned b64
//   reads, (2k+2tx)%32 distinct banks; <=2-way write conflicts)
// Inner loop: 2 LDS reads (b64+b64) + 2 packed fma per k (splats fold to op_sel).
// ---------------------------------------------------------------------------
__global__ __launch_bounds__(256, 2) void k1_gemm(
    const float* __restrict__ nodes, const float* __restrict__ W1,
    const float* __restrict__ b1, float* __restrict__ At, float* __restrict__ Bt)
{
    __shared__ float nt[128][34];     // 17408 B, k-chunked nodes^T
    __shared__ f32x2 wab[DIM][17];    // 34816 B, full-k {Wa,Wb}^T

    const int t  = threadIdx.x;
    const int i0 = (blockIdx.x & 31) * 32;
    const int d0 = (blockIdx.x >> 5) * 16;

    // ---- stage wab once (full 256 k), coalesced float4 global reads
    {
        const int m = t & 15, s = t >> 4;          // s = d_local 0..15
        const float* srcA = W1 + (d0 + s) * (2 * DIM);
        const float* srcB = srcA + DIM;
        #pragma unroll
        for (int rep = 0; rep < 4; ++rep) {
            const int k = rep * 64 + m * 4;
            float4 va = *(const float4*)(srcA + k);
            float4 vb = *(const float4*)(srcB + k);
            wab[k+0][s] = f32x2{va.x, vb.x};
            wab[k+1][s] = f32x2{va.y, vb.y};
            wab[k+2][s] = f32x2{va.z, vb.z};
            wab[k+3][s] = f32x2{va.w, vb.w};
        }
    }

    const int tx = t & 15;     // i pair: i = i0 + tx*2
    const int ty = t >> 4;     // d:      d = d0 + ty
    const int sm = t & 7, ss = t >> 3;             // staging map for nt
    const float* nsrc = nodes + (i0 + ss) * DIM;

    f32x2 accA = {0.f, 0.f}, accB = {0.f, 0.f};

    for (int kc = 0; kc < DIM; kc += 128) {
        __syncthreads();   // orders wab stage (iter 0) / nt readers (iter 1)
        #pragma unroll
        for (int rep = 0; rep < 4; ++rep) {
            const int k = rep * 32 + sm * 4;
            float4 v = *(const float4*)(nsrc + kc + k);
            nt[k+0][ss] = v.x; nt[k+1][ss] = v.y;
            nt[k+2][ss] = v.z; nt[k+3][ss] = v.w;
        }
        __syncthreads();

        #pragma unroll 8
        for (int k = 0; k < 128; ++k) {
            f32x2 av = *(const f32x2*)&nt[k][tx * 2];   // {nodes[i,kk], nodes[i+1,kk]}
            f32x2 wv = wab[kc + k][ty];                 // {Wa[d,kk], Wb[d,kk]}
            f32x2 waa = __builtin_shufflevector(wv, wv, 0, 0);
            f32x2 wbb = __builtin_shufflevector(wv, wv, 1, 1);
            accA = __builtin_elementwise_fma(av, waa, accA);
            accB = __builtin_elementwise_fma(av, wbb, accB);
        }
    }

    const int d = d0 + ty;
    const int i = i0 + tx * 2;
    const float bb = b1[d];
    f32x2 oa = accA + f32x2{bb, bb};
    *(f32x2*)&At[d * N_NODES + i] = oa;
    *(f32x2*)&Bt[d * N_NODES + i] = accB;
}

// ---------------------------------------------------------------------------
// k2 v4: out[i,j] = sigmoid( sum_d relu(At[d][i]+Bt[d][j]) * w2[d] + b2 )
// Tile 32x32, grid 1024. D chunked 2x128 -> LDS 32 KB -> 4-5 blocks/CU
// (barrier/stage phases hidden by co-resident blocks).
// Packed-f32 core: per d per 2x2 micro: 2 pk_add (op_sel splat) + 4 v_max +
// 2 pk_fma = 8 VALU instr / 4 elems (2/elem; scalar was 3/elem).
// LDS reads conflict-free: a-read 4 addrs broadcast x16, b-read 16 distinct banks.
// Staging: flat*16B contiguous LDS writes, coalesced b128 global reads.
// ---------------------------------------------------------------------------
__global__ __launch_bounds__(256, 4) void k2_pair(
    const float* __restrict__ At, const float* __restrict__ Bt,
    const float* __restrict__ W2, const float* __restrict__ b2,
    float* __restrict__ out)
{
    __shared__ float As[128][32];   // 16 KB
    __shared__ float Bs[128][32];   // 16 KB

    const int t  = threadIdx.x;
    const int i0 = (blockIdx.x & 31) * 32;
    const int j0 = (blockIdx.x >> 5) * 32;
    const int tx = t & 15;   // j pair: j = j0 + tx*2
    const int ty = t >> 4;   // i pair: i = i0 + ty*2

    f32x2 acc0 = {0.f, 0.f};   // row i,   cols (j, j+1)
    f32x2 acc1 = {0.f, 0.f};   // row i+1

    for (int dc = 0; dc < DIM; dc += 128) {
        __syncthreads();   // protect previous chunk's readers
        #pragma unroll
        for (int rep = 0; rep < 4; ++rep) {
            const int flat = rep * 256 + t;      // 0..1023
            const int row  = flat >> 3;          // 0..127
            const int c4   = (flat & 7) * 4;
            *(float4*)&As[row][c4] = *(const float4*)(At + (dc+row) * N_NODES + i0 + c4);
            *(float4*)&Bs[row][c4] = *(const float4*)(Bt + (dc+row) * N_NODES + j0 + c4);
        }
        __syncthreads();

        #pragma unroll 8
        for (int d = 0; d < 128; ++d) {
            const float w = W2[dc + d];                   // uniform -> s_load
            f32x2 wv = {w, w};
            f32x2 a2 = *(const f32x2*)&As[d][ty * 2];     // i-pair
            f32x2 bj = *(const f32x2*)&Bs[d][tx * 2];     // j-pair
            f32x2 axx = __builtin_shufflevector(a2, a2, 0, 0);
            f32x2 ayy = __builtin_shufflevector(a2, a2, 1, 1);
            acc0 = __builtin_elementwise_fma(relu2(axx + bj), wv, acc0);
            acc1 = __builtin_elementwise_fma(relu2(ayy + bj), wv, acc1);
        }
    }

    const float bb = b2[0];
    f32x2 x0 = acc0 + f32x2{bb, bb};
    f32x2 x1 = acc1 + f32x2{bb, bb};
    float2 o0, o1;
    o0.x = 1.0f / (1.0f + __expf(-x0.x));
    o0.y = 1.0f / (1.0f + __expf(-x0.y));
    o1.x = 1.0f / (1.0f + __expf(-x1.x));
    o1.y = 1.0f / (1.0f + __expf(-x1.y));

    const int r = i0 + ty * 2;
    const int c = j0 + tx * 2;
    *(float2*)&out[(r    ) * N_NODES + c] = o0;
    *(float2*)&out[(r + 1) * N_NODES + c] = o1;
}

extern "C" void kernel_launch(void* const* d_in, const int* in_sizes, int n_in,
                              void* d_out, int out_size, void* d_ws, size_t ws_size,
                              hipStream_t stream) {
    const float* nodes = (const float*)d_in[0];   // (1024, 256)
    const float* W1    = (const float*)d_in[1];   // (256, 512)
    const float* b1    = (const float*)d_in[2];   // (256,)
    const float* W2    = (const float*)d_in[3];   // (1, 256)
    const float* b2    = (const float*)d_in[4];   // (1,)
    float* out = (float*)d_out;                   // (1024, 1024)

    float* At = (float*)d_ws;                     // [256][1024] = 1 MB
    float* Bt = At + DIM * N_NODES;               // [256][1024] = 1 MB

    k1_gemm<<<512,  256, 0, stream>>>(nodes, W1, b1, At, Bt);
    k2_pair<<<1024, 256, 0, stream>>>(At, Bt, W2, b2, out);
}